// Round 14
// baseline (288.409 us; speedup 1.0000x reference)
//
#include <hip/hip_runtime.h>

#define H 64
#define NN 100000
#define NE 1000000
#define EPS 1e-6f

// ROUND 20: r19 budget: streaming 615MB ~= 98us; atomic sector service
// 244MB @ ~1.1TB/s (r6/r11/r12-validated rate) ~= 222us; measured 263 =
// ~85% atomic-bound + ~40us exposure. CSR/gather alternative arithmetics
// to ~300us (sort+gather+stream) -- stay with atomics, squeeze exposure:
//  1) Wl is DEAD after the GEMM: union the per-wave slices into it.
//     LDS 41.2 -> 25.6KB -> 6 blocks/CU (was 3). More staggered blocks =
//     atomic bursts of one block hide under others' GEMMs.
//  2) slice row stride 64 -> 65 floats: the 4 q-groups hit distinct banks
//     on the scatter writes (was 4-way on every one of 32 store instrs).
//     All slice accesses are scalar -- no alignment constraint.
// Everything else byte-identical to r19 (MFMA f16 GEMM, one W barrier,
// one new pre-slice barrier, row-contiguous atomics, NT stores).

typedef __attribute__((ext_vector_type(4))) float f32v4;
typedef __attribute__((ext_vector_type(4))) float floatx4;
typedef _Float16 half8 __attribute__((ext_vector_type(8)));
typedef _Float16 half4 __attribute__((ext_vector_type(4)));

#define SLICE_STRIDE 65  // floats; scalar access only -> no align issue

__global__ __launch_bounds__(256, 3) void edge_mfma(
    const float* __restrict__ nodes, const float* __restrict__ edges,
    const int* __restrict__ senders, const int* __restrict__ receivers,
    const float* __restrict__ We, const float* __restrict__ be,
    const float* __restrict__ ln_s, const float* __restrict__ ln_b,
    float* recv_agg, float* __restrict__ edges_out) {
  // 25.6 KB union: phase 1 = W^T f16 [col][k] (400B row stride);
  // phase 2 (after barrier 2) = 4 per-wave 16x65-float slices (16.9 KB).
  __shared__ __align__(16) _Float16 Wl[64][200];
  const int tid = threadIdx.x;
  const int e0 = blockIdx.x * 64;               // NE % 64 == 0: grid exact

  // ---- W stage (once): thread t -> col = t&63, k-seg = (t>>6)*48.
  {
    const int col = tid & 63;
    const int ks = (tid >> 6) * 48;
#pragma unroll 4
    for (int m = 0; m < 12; ++m) {
      const int k4 = ks + m * 4;
      half4 hv;
      hv.x = (_Float16)We[(k4 + 0) * 64 + col];
      hv.y = (_Float16)We[(k4 + 1) * 64 + col];
      hv.z = (_Float16)We[(k4 + 2) * 64 + col];
      hv.w = (_Float16)We[(k4 + 3) * 64 + col];
      *(half4*)&Wl[col][k4] = hv;
    }
  }

  const int w = tid >> 6;    // wave 0..3: edges [e0+16w, e0+16w+16)
  const int l = tid & 63;
  const int q = l >> 4;      // 0..3: k-subblock / D row-quad
  const int r15 = l & 15;    // A row (edge) for frags; D col
  const int geR = e0 + w * 16 + r15;
  const int sI = senders[geR];
  const int rI = receivers[geR];
  const float* rowp[3] = {edges + (size_t)geR * H, nodes + (size_t)sI * H,
                          nodes + (size_t)rI * H};

  __syncthreads();  // barrier 1: W ready

  floatx4 acc[4];
#pragma unroll
  for (int ct = 0; ct < 4; ++ct) acc[ct] = (floatx4){0.f, 0.f, 0.f, 0.f};

  // 6 k-chunks of 32. A frag: lane reads 8 consecutive f32 of its edge row
  // (row = r15, k = kc*32 + q*8) -> cvt f16. 4 lanes/row cover 128B within
  // one instr pair -> fully coalesced, no sub-line amplification.
#pragma unroll
  for (int kc = 0; kc < 6; ++kc) {
    const float* src = rowp[kc >> 1] + (kc & 1) * 32 + q * 8;
    const f32v4 x0 = *(const f32v4*)(src + 0);
    const f32v4 x1 = *(const f32v4*)(src + 4);
    half8 af;
    af[0] = (_Float16)x0.x; af[1] = (_Float16)x0.y;
    af[2] = (_Float16)x0.z; af[3] = (_Float16)x0.w;
    af[4] = (_Float16)x1.x; af[5] = (_Float16)x1.y;
    af[6] = (_Float16)x1.z; af[7] = (_Float16)x1.w;
    const int kb = kc * 32 + q * 8;
    // B frags: col = ct*16 + r15, k = kb..kb+8 (k-contiguous in Wl)
    const half8 b0 = *(const half8*)&Wl[0 + r15][kb];
    const half8 b1 = *(const half8*)&Wl[16 + r15][kb];
    const half8 b2 = *(const half8*)&Wl[32 + r15][kb];
    const half8 b3 = *(const half8*)&Wl[48 + r15][kb];
    acc[0] = __builtin_amdgcn_mfma_f32_16x16x32_f16(af, b0, acc[0], 0, 0, 0);
    acc[1] = __builtin_amdgcn_mfma_f32_16x16x32_f16(af, b1, acc[1], 0, 0, 0);
    acc[2] = __builtin_amdgcn_mfma_f32_16x16x32_f16(af, b2, acc[2], 0, 0, 0);
    acc[3] = __builtin_amdgcn_mfma_f32_16x16x32_f16(af, b3, acc[3], 0, 0, 0);
  }

  // ---- epilogue (register side), frag layout: lane holds cols
  // {ct*16+r15} of edges E_i = q*4+i; acc[ct][i] = D[E_i][ct*16+r15].
  float bev[4], ssv[4], llv[4];
#pragma unroll
  for (int ct = 0; ct < 4; ++ct) {
    bev[ct] = be[ct * 16 + r15];
    ssv[ct] = ln_s[ct * 16 + r15];
    llv[ct] = ln_b[ct * 16 + r15];
  }
  float nv[4][4], tv[4][4];  // [ct][i]
  float s1[4] = {0.f, 0.f, 0.f, 0.f}, s2[4] = {0.f, 0.f, 0.f, 0.f};
#pragma unroll
  for (int i = 0; i < 4; ++i) {
    const int geE = e0 + w * 16 + q * 4 + i;
#pragma unroll
    for (int ct = 0; ct < 4; ++ct) {
      const float n = acc[ct][i] + bev[ct];
      // residual: L2-hot from the GEMM phase reads
      const float rr = edges[(size_t)geE * H + ct * 16 + r15];
      nv[ct][i] = n;
      const float t = n + rr;
      tv[ct][i] = t;
      s1[i] += t;
      s2[i] = fmaf(t, t, s2[i]);
    }
  }
  // per-edge LN sums: reduce across the 16 lanes of this quadrant
#pragma unroll
  for (int i = 0; i < 4; ++i) {
    s1[i] += __shfl_xor(s1[i], 1, 64); s2[i] += __shfl_xor(s2[i], 1, 64);
    s1[i] += __shfl_xor(s1[i], 2, 64); s2[i] += __shfl_xor(s2[i], 2, 64);
    s1[i] += __shfl_xor(s1[i], 4, 64); s2[i] += __shfl_xor(s2[i], 4, 64);
    s1[i] += __shfl_xor(s1[i], 8, 64); s2[i] += __shfl_xor(s2[i], 8, 64);
  }

  __syncthreads();  // barrier 2: all waves done with Wl -> reuse as slices
  float* sl = (float*)&Wl[0][0] + w * (16 * SLICE_STRIDE);  // per-wave

  // n -> slice (transpose; stride 65: q-groups on distinct banks) -> one
  // row-contiguous atomic instr per edge (256B row, 8 sectors fully
  // covered: the r12 1x-amplification win)
#pragma unroll
  for (int i = 0; i < 4; ++i)
#pragma unroll
    for (int ct = 0; ct < 4; ++ct)
      sl[(q * 4 + i) * SLICE_STRIDE + ct * 16 + r15] = nv[ct][i];
#pragma unroll 4
  for (int e2 = 0; e2 < 16; ++e2) {
    const int rb = __shfl(rI, e2, 64);  // edge e2's receiver (lane e2)
    const float v = sl[e2 * SLICE_STRIDE + l];  // stride-1: bank-clean
    atomicAdd(recv_agg + (size_t)rb * H + l, v);
  }
  // LN output -> slice -> coalesced NT dword stores (256B/instr)
#pragma unroll
  for (int i = 0; i < 4; ++i) {
    const float mean = s1[i] * (1.0f / 64.0f);
    const float var = s2[i] * (1.0f / 64.0f) - mean * mean;
    const float rstd = rsqrtf(var + EPS);
#pragma unroll
    for (int ct = 0; ct < 4; ++ct)
      sl[(q * 4 + i) * SLICE_STRIDE + ct * 16 + r15] =
          (tv[ct][i] - mean) * rstd * ssv[ct] + llv[ct];
  }
#pragma unroll 4
  for (int e2 = 0; e2 < 16; ++e2) {
    const float v = sl[e2 * SLICE_STRIDE + l];
    __builtin_nontemporal_store(
        v, edges_out + (size_t)(e0 + w * 16 + e2) * H + l);
  }
}

// ---- node kernel: unchanged (not the bottleneck, ~21 µs).
__global__ __launch_bounds__(256, 3) void node_tiled(
    const float* __restrict__ nodes, const float* recv_agg,
    const float* __restrict__ Wn, const float* __restrict__ bn,
    const float* __restrict__ ln_s, const float* __restrict__ ln_b,
    float* nodes_out) {
  __shared__ __align__(16) float aT[64 * 64];    // 16 KB: [k-k0][n]
  __shared__ __align__(16) float Wb[128 * 64];   // 32 KB
  const int tid = threadIdx.x;
  const int n0 = blockIdx.x * 64;

#pragma unroll
  for (int t = 0; t < 8; ++t) {
    int ci = t * 256 + tid;
    *(float4*)(&Wb[ci * 4]) = *(const float4*)(Wn + ci * 4);
  }

  float acc[4][4];
#pragma unroll
  for (int j = 0; j < 4; ++j)
#pragma unroll
    for (int i = 0; i < 4; ++i) acc[j][i] = 0.0f;

  const int te = (tid >> 4) * 4;
  const int tc = (tid & 15) * 4;

#pragma unroll
  for (int p = 0; p < 2; ++p) {
    const int k0 = 64 * p;
#pragma unroll
    for (int t = 0; t < 4; ++t) {
      int ci = t * 256 + tid;                     // 1024 float4
      int n = ci & 63, kq = ci >> 6;              // kq 0..15
      int kg = k0 + kq * 4;
      int gn = n0 + n;
      int gnc = gn < NN ? gn : NN - 1;
      const float* src = (kg < 64) ? (nodes + (size_t)gnc * H + kg)
                                   : (recv_agg + (size_t)gnc * H + (kg - 64));
      float4 v = *(const float4*)src;
      aT[(kq * 4 + 0) * 64 + n] = v.x;
      aT[(kq * 4 + 1) * 64 + n] = v.y;
      aT[(kq * 4 + 2) * 64 + n] = v.z;
      aT[(kq * 4 + 3) * 64 + n] = v.w;
    }
    __syncthreads();
#pragma unroll 4
    for (int kk = 0; kk < 64; ++kk) {
      float4 a4 = *(const float4*)(&aT[kk * 64 + te]);
      float4 w4 = *(const float4*)(&Wb[(k0 + kk) * 64 + tc]);
      float av[4] = {a4.x, a4.y, a4.z, a4.w};
      float wv[4] = {w4.x, w4.y, w4.z, w4.w};
#pragma unroll
      for (int j = 0; j < 4; ++j)
#pragma unroll
        for (int i = 0; i < 4; ++i) acc[j][i] += av[j] * wv[i];
    }
    __syncthreads();
  }

  const float4 bev = *(const float4*)(bn + tc);
  const float4 sev = *(const float4*)(ln_s + tc);
  const float4 biv = *(const float4*)(ln_b + tc);
#pragma unroll
  for (int j = 0; j < 4; ++j) {
    int gn = n0 + te + j;
    bool valid = gn < NN;
    float4 nv;
    if (valid) nv = *(const float4*)(nodes + (size_t)gn * H + tc);
    else { nv.x = nv.y = nv.z = nv.w = 0.0f; }
    float t0 = acc[j][0] + bev.x + nv.x;
    float t1 = acc[j][1] + bev.y + nv.y;
    float t2 = acc[j][2] + bev.z + nv.z;
    float t3 = acc[j][3] + bev.w + nv.w;
    float s1 = t0 + t1 + t2 + t3;
    float s2 = t0 * t0 + t1 * t1 + t2 * t2 + t3 * t3;
    s1 += __shfl_xor(s1, 1, 64); s2 += __shfl_xor(s2, 1, 64);
    s1 += __shfl_xor(s1, 2, 64); s2 += __shfl_xor(s2, 2, 64);
    s1 += __shfl_xor(s1, 4, 64); s2 += __shfl_xor(s2, 4, 64);
    s1 += __shfl_xor(s1, 8, 64); s2 += __shfl_xor(s2, 8, 64);
    float mean = s1 * (1.0f / 64.0f);
    float var = s2 * (1.0f / 64.0f) - mean * mean;
    float rstd = rsqrtf(var + EPS);
    if (valid) {
      float4 o;
      o.x = (t0 - mean) * rstd * sev.x + biv.x;
      o.y = (t1 - mean) * rstd * sev.y + biv.y;
      o.z = (t2 - mean) * rstd * sev.z + biv.z;
      o.w = (t3 - mean) * rstd * sev.w + biv.w;
      *(float4*)(nodes_out + (size_t)gn * H + tc) = o;
    }
  }
}

extern "C" void kernel_launch(void* const* d_in, const int* in_sizes, int n_in,
                              void* d_out, int out_size, void* d_ws, size_t ws_size,
                              hipStream_t stream) {
  const float* nodes      = (const float*)d_in[0];
  const float* edges      = (const float*)d_in[1];
  const int*   senders    = (const int*)d_in[2];
  const int*   receivers  = (const int*)d_in[3];
  const float* We         = (const float*)d_in[4];
  const float* be         = (const float*)d_in[5];
  const float* Wn         = (const float*)d_in[6];
  const float* bn         = (const float*)d_in[7];
  const float* ln_n_scale = (const float*)d_in[8];
  const float* ln_n_bias  = (const float*)d_in[9];
  const float* ln_e_scale = (const float*)d_in[10];
  const float* ln_e_bias  = (const float*)d_in[11];

  float* out = (float*)d_out;
  float* nodes_out = out;                       // [NN,64]; doubles as recv_agg
  float* edges_out = out + (size_t)NN * H;      // [NE,64]

  (void)hipMemsetAsync(nodes_out, 0, (size_t)NN * H * sizeof(float), stream);
  edge_mfma<<<NE / 64, 256, 0, stream>>>(
      nodes, edges, senders, receivers, We, be, ln_e_scale, ln_e_bias,
      nodes_out, edges_out);
  node_tiled<<<(NN + 63) / 64, 256, 0, stream>>>(nodes, nodes_out, Wn, bn,
                                                 ln_n_scale, ln_n_bias, nodes_out);
}